// Round 1
// baseline (424.156 us; speedup 1.0000x reference)
//
#include <hip/hip_runtime.h>

// nnmodel_35708358099045: tiny fixed-graph GNN, B=524288 independent elements.
// ND=40 grid nodes, HN=10 hidden nodes, HF=8 features, fp32 throughout.
// One thread per batch element; graph structure hard-coded (compile-time).
//
// Memory per element: read 640 B (x 160 + z 320 + y 160), write 160 B.
// Total 419 MB -> ~67 us roofline at 6.3 TB/s. Compute ~2.4 GFLOP total.

#define HN 10
#define ND 40
#define HF 8

__global__ __launch_bounds__(256) void gnn_kernel(
    const float* __restrict__ x,          // [B, 40]
    const float* __restrict__ z,          // [B, 10, 8]
    const float* __restrict__ y,          // [B, 40]
    const float* __restrict__ enc_rel_w,  // [8, 1]
    const float* __restrict__ enc_rel_b,  // [8]
    const float* __restrict__ enc_root_w, // [8, 8]
    const float* __restrict__ pred_rel_w, // [8, 8]
    const float* __restrict__ pred_rel_b, // [8]
    const float* __restrict__ pred_root_w,// [8, 8]
    const float* __restrict__ dec_rel_w,  // [1, 8]
    const float* __restrict__ dec_rel_b,  // [1]
    const float* __restrict__ dec_root_w, // [1, 1]
    float* __restrict__ out,              // [B, 40]
    int B)
{
    int b = blockIdx.x * blockDim.x + threadIdx.x;
    if (b >= B) return;

    // w = np.float32(np.exp(-(1/3)^2))
    const float w = 0.8948393168143698f;

    // ---- load x[40] (10 x float4, 16B-aligned: 40 floats * b = 160B) ----
    float xv[ND];
    const float4* xp = (const float4*)(x + (size_t)b * ND);
    #pragma unroll
    for (int k = 0; k < 10; ++k) {
        float4 v = xp[k];
        xv[4*k+0] = v.x; xv[4*k+1] = v.y; xv[4*k+2] = v.z; xv[4*k+3] = v.w;
    }

    // ---- encoder aggregation: agg[j] = sum_{d=-3}^{2} x[(4j+d) mod 40] ----
    float agg[HN];
    agg[0] = xv[37] + xv[38] + xv[39] + xv[0] + xv[1] + xv[2];
    #pragma unroll
    for (int j = 1; j < HN; ++j)
        agg[j] = xv[4*j-3] + xv[4*j-2] + xv[4*j-1] + xv[4*j] + xv[4*j+1] + xv[4*j+2];

    // ---- encoder GraphConv: z1[j][f] = relu(agg[j]*erw[f] + erb[f] + z[j]·eroot[f]) ----
    float z1[HN][HF];
    const float4* zp = (const float4*)(z + (size_t)b * (HN*HF));
    #pragma unroll
    for (int j = 0; j < HN; ++j) {
        float zr[HF];
        float4 v0 = zp[2*j], v1 = zp[2*j+1];
        zr[0]=v0.x; zr[1]=v0.y; zr[2]=v0.z; zr[3]=v0.w;
        zr[4]=v1.x; zr[5]=v1.y; zr[6]=v1.z; zr[7]=v1.w;
        #pragma unroll
        for (int f = 0; f < HF; ++f) {
            float acc = agg[j] * enc_rel_w[f] + enc_rel_b[f];
            #pragma unroll
            for (int g = 0; g < HF; ++g)
                acc += zr[g] * enc_root_w[f*HF + g];
            z1[j][f] = fmaxf(acc, 0.0f);
        }
    }

    // ---- predictor GraphConv + decoder row-reduction ----
    // agg2[j] = z1[j] + w*(z1[j-1] + z1[j+1])  (ring mod 10)
    // z2[j][f] = relu(agg2[j]·prel[f] + prb[f] + z1[j]·proot[f])
    // s2[j] = z2[j]·drel   (decoder lin_rel folded in; z2 never materialized)
    float s2[HN];
    #pragma unroll
    for (int j = 0; j < HN; ++j) {
        const int jm = (j + HN - 1) % HN;
        const int jp = (j + 1) % HN;
        float a2[HF];
        #pragma unroll
        for (int f = 0; f < HF; ++f)
            a2[f] = z1[j][f] + w * (z1[jm][f] + z1[jp][f]);
        float sj = 0.0f;
        #pragma unroll
        for (int f = 0; f < HF; ++f) {
            float acc = pred_rel_b[f];
            #pragma unroll
            for (int g = 0; g < HF; ++g)
                acc += a2[g] * pred_rel_w[f*HF + g];
            #pragma unroll
            for (int g = 0; g < HF; ++g)
                acc += z1[j][g] * pred_root_w[f*HF + g];
            sj += fmaxf(acc, 0.0f) * dec_rel_w[f];
        }
        s2[j] = sj;
    }

    // ---- decoder: A_DEC structure folds to neighbor-pair sums ----
    // out[4k+0] = s2[k];             out[4k+1] = s2[k] + s2[k+1];
    // out[4k+2] = s2[k] + s2[k+1];   out[4k+3] = s2[k+1];   (k+1 mod 10)
    // plus dec_rel_b + y * dec_root_w
    const float drb = dec_rel_b[0];
    const float droot = dec_root_w[0];
    const float4* yp = (const float4*)(y + (size_t)b * ND);
    float4* op = (float4*)(out + (size_t)b * ND);
    #pragma unroll
    for (int k = 0; k < 10; ++k) {
        const int k1 = (k + 1) % HN;
        const float pair = s2[k] + s2[k1];
        float4 vy = yp[k];
        float4 vo;
        vo.x = s2[k] + drb + vy.x * droot;
        vo.y = pair  + drb + vy.y * droot;
        vo.z = pair  + drb + vy.z * droot;
        vo.w = s2[k1] + drb + vy.w * droot;
        op[k] = vo;
    }
}

extern "C" void kernel_launch(void* const* d_in, const int* in_sizes, int n_in,
                              void* d_out, int out_size, void* d_ws, size_t ws_size,
                              hipStream_t stream) {
    const float* x          = (const float*)d_in[0];
    const float* z          = (const float*)d_in[1];
    const float* y          = (const float*)d_in[2];
    const float* enc_rel_w  = (const float*)d_in[3];
    const float* enc_rel_b  = (const float*)d_in[4];
    const float* enc_root_w = (const float*)d_in[5];
    const float* pred_rel_w = (const float*)d_in[6];
    const float* pred_rel_b = (const float*)d_in[7];
    const float* pred_root_w= (const float*)d_in[8];
    const float* dec_rel_w  = (const float*)d_in[9];
    const float* dec_rel_b  = (const float*)d_in[10];
    const float* dec_root_w = (const float*)d_in[11];
    float* out = (float*)d_out;

    const int B = in_sizes[0] / ND;  // 524288
    const int threads = 256;
    const int blocks = (B + threads - 1) / threads;
    gnn_kernel<<<blocks, threads, 0, stream>>>(
        x, z, y, enc_rel_w, enc_rel_b, enc_root_w,
        pred_rel_w, pred_rel_b, pred_root_w,
        dec_rel_w, dec_rel_b, dec_root_w, out, B);
}